// Round 8
// baseline (189.220 us; speedup 1.0000x reference)
//
#include <hip/hip_runtime.h>

#define B_   8
#define H_   112
#define W_   112
#define HW_  12544
#define C_   128
#define NH_  4
#define HD_  32
#define KK_  49
#define N_   100352
#define SCALE_ 0.17677669529663687f   // 1/sqrt(32)

typedef __attribute__((ext_vector_type(4))) float floatx4;
typedef __attribute__((ext_vector_type(4))) _Float16 halfx4;
typedef __attribute__((ext_vector_type(8))) _Float16 half8;

// ---------------- K0: weight prep ----------------
// R7: both weight matrices -> single fp16 plane. Error analysis: logits are
// tiny (|q.k|*scale ~ 0.05, softmax near-uniform) so q/k rounding at fp16
// u=2^-11 perturbs the output ~1e-5; v-path adds ~3e-5 after proj.
__global__ __launch_bounds__(256) void k_wt(
    const float* __restrict__ qw, const float* __restrict__ pw,
    _Float16* __restrict__ qwf, _Float16* __restrict__ pwf)
{
  const int idx = blockIdx.x * 256 + threadIdx.x;
  if (idx < 384 * 128) qwf[idx] = (_Float16)qw[idx];
  if (idx < 128 * 128) pwf[idx] = (_Float16)pw[idx];
}

// ---------------- K1: QKV via fp16 MFMA + q.k dot + v store ----------------
// Block = 64 px, 4 waves; wave w = head w. LDS 17.4 KB.
// R8: 3-pass split at (256,4). HISTORY (regimes matter):
//   R1/R2: pass-split in the SPLIT-BF16 regime (2x B-frags, 2 planes x 2
//     matrices -> live ~150) spilled at both 128 and 168 caps. FALSIFIED THERE.
//   R7: fp16 single plane: frags halved; single-pass = 96 AGPR + 100 VGPR
//     -> still 2 waves/SIMD, 43.8 us, MfmaUtil 8% — latency-starved.
//   R8 (this): fp16 regime re-opens the split: peak live = QK-half pass
//     ~ 32 acc + 16 bb + 16 wfrag + addr ~ 110 < 128 cap -> 4 blk/CU.
//   Passes: V (store early), QK hd 0..15, QK hd 16..31 (part[] carried).
//   Tripwire: FETCH/WRITE balloon = spill -> revert to R7 single-pass.
// Other falsified: R5 32-px tile (MFMA:weight-load ratio halves -> 100 us).
__global__ __launch_bounds__(256, 4) void k_qkv(
    const float* __restrict__ x, const _Float16* __restrict__ qwf,
    const float* __restrict__ qb,
    _Float16* __restrict__ vbuf, float* __restrict__ dotbuf)
{
  __shared__ __align__(16) _Float16 xf[64 * 136];  // [px][c] fp16
  const int tid = threadIdx.x;
  const int b   = blockIdx.x / 196;
  const int hw0 = (blockIdx.x % 196) * 64;

  { // stage: thread = (c,c+1) x 4 px; coalesced float4 loads, packed writes
    const float* xb = x + (size_t)b * C_ * HW_ + hw0;
    const int p4 = (tid & 15) * 4;
#pragma unroll
    for (int rep = 0; rep < 4; ++rep) {
      const int c = ((tid >> 4) + rep * 16) * 2;
      const float4 fa = *(const float4*)(xb + (size_t)c * HW_ + p4);
      const float4 fb = *(const float4*)(xb + (size_t)(c + 1) * HW_ + p4);
      const float va[4] = {fa.x, fa.y, fa.z, fa.w};
      const float vb[4] = {fb.x, fb.y, fb.z, fb.w};
#pragma unroll
      for (int i = 0; i < 4; ++i) {
        union { _Float16 h[2]; unsigned u; } pk;
        pk.h[0] = (_Float16)va[i];
        pk.h[1] = (_Float16)vb[i];
        *(unsigned*)(xf + (p4 + i) * 136 + c) = pk.u;
      }
    }
  }
  __syncthreads();

  const int w    = __builtin_amdgcn_readfirstlane(tid >> 6);
  const int l    = tid & 63;
  const int m16  = l & 15;
  const int quad = l >> 4;
  const size_t dbase = (size_t)(b * NH_ + w) * HW_ + hw0;

  // ---- pass V: rows [256 + w*32, +32); store the 26 MB write early ----
  {
    floatx4 av[2][4];
#pragma unroll
    for (int t = 0; t < 2; ++t)
#pragma unroll
      for (int p = 0; p < 4; ++p) av[t][p] = (floatx4){0.f, 0.f, 0.f, 0.f};

    for (int ks = 0; ks < 4; ++ks) {
      half8 bb[4];
#pragma unroll
      for (int p = 0; p < 4; ++p)
        bb[p] = *(const half8*)(xf + (p * 16 + m16) * 136 + ks * 32 + quad * 8);
#pragma unroll
      for (int t = 0; t < 2; ++t) {
        const size_t vo = (size_t)(256 + w * 32 + t * 16 + m16) * C_ + ks * 32 + quad * 8;
        const half8 wa = *(const half8*)(qwf + vo);
#pragma unroll
        for (int p = 0; p < 4; ++p)
          av[t][p] = __builtin_amdgcn_mfma_f32_16x16x32_f16(wa, bb[p], av[t][p], 0, 0, 0);
      }
    }
#pragma unroll
    for (int t = 0; t < 2; ++t) {
      float bias[4];
#pragma unroll
      for (int r = 0; r < 4; ++r) bias[r] = qb[256 + w * 32 + t * 16 + quad * 4 + r];
#pragma unroll
      for (int p = 0; p < 4; ++p) {
        halfx4 hv;
#pragma unroll
        for (int r = 0; r < 4; ++r) hv[r] = (_Float16)(av[t][p][r] + bias[r]);
        _Float16* vp = vbuf + (dbase + p * 16 + m16) * HD_ + t * 16 + quad * 4;
        *(halfx4*)vp = hv;
      }
    }
  }

  // ---- passes QK0/QK1: one hd-half each; dot accumulates in part[] ----
  float part[4] = {0.f, 0.f, 0.f, 0.f};
#pragma unroll 1
  for (int half = 0; half < 2; ++half) {
    const int qrow = w * 32 + half * 16;   // rows in Wq
    const int krow = 128 + qrow;           // rows in Wk
    floatx4 aq[4], ak[4];
#pragma unroll
    for (int p = 0; p < 4; ++p) {
      aq[p] = (floatx4){0.f, 0.f, 0.f, 0.f};
      ak[p] = (floatx4){0.f, 0.f, 0.f, 0.f};
    }
    for (int ks = 0; ks < 4; ++ks) {
      half8 bb[4];
#pragma unroll
      for (int p = 0; p < 4; ++p)
        bb[p] = *(const half8*)(xf + (p * 16 + m16) * 136 + ks * 32 + quad * 8);
      const half8 qw8 = *(const half8*)(qwf + (size_t)(qrow + m16) * C_ + ks * 32 + quad * 8);
      const half8 kw8 = *(const half8*)(qwf + (size_t)(krow + m16) * C_ + ks * 32 + quad * 8);
#pragma unroll
      for (int p = 0; p < 4; ++p) {
        aq[p] = __builtin_amdgcn_mfma_f32_16x16x32_f16(qw8, bb[p], aq[p], 0, 0, 0);
        ak[p] = __builtin_amdgcn_mfma_f32_16x16x32_f16(kw8, bb[p], ak[p], 0, 0, 0);
      }
    }
    float bq[4], bk[4];
#pragma unroll
    for (int r = 0; r < 4; ++r) {
      bq[r] = qb[qrow + quad * 4 + r];
      bk[r] = qb[krow + quad * 4 + r];
    }
#pragma unroll
    for (int p = 0; p < 4; ++p)
#pragma unroll
      for (int r = 0; r < 4; ++r)
        part[p] += (aq[p][r] + bq[r]) * (ak[p][r] + bk[r]);
  }

#pragma unroll
  for (int p = 0; p < 4; ++p) {
    float s = part[p];
    s += __shfl_xor(s, 16);
    s += __shfl_xor(s, 32);
    if (l < 16) dotbuf[dbase + p * 16 + l] = s * SCALE_;
  }
}

// ---------------- K2: neighborhood softmax + A*V -> fp16 out --------------
// R4 locality structure (measured win, keep):
//  - `at` table fp32 (fp16 table REGRESSED: 6 blk/CU x 62 KB V-window
//    thrashed the 4 MB XCD-L2; fp32 = 51 KB LDS pins 3 blk/CU).
//  - V is fp16: window 31 KB/block; concurrent set 3x32x31KB ~ 3 MB < L2.
//  - XCD-chunked block swizzle: grid 1568 = 8 XCD x 196; 196 = 4 whole
//    (head,b) groups of 49 tiles -> each group's entire V (0.8 MB) stays in
//    one XCD's L2; window overlap becomes L2 hits.
// R6: ao output single fp16 plane (write 52 -> 26 MB) — measured win, keep.
__global__ __launch_bounds__(256) void k_attn(
    const _Float16* __restrict__ vbuf, const float* __restrict__ dotbuf,
    const float* __restrict__ rpb, _Float16* __restrict__ aof)
{
  __shared__ __align__(16) float at[KK_ * 256];
  __shared__ float rsum[256];
  const int tid  = threadIdx.x;
  const int blk  = ((int)blockIdx.x & 7) * 196 + ((int)blockIdx.x >> 3);
  const int head = blk / 392;
  const int rem  = blk % 392;
  const int b    = rem / 49;
  const int t49  = rem % 49;
  const int r0 = (t49 / 7) * 16;
  const int w0 = (t49 % 7) * 16;
  const float* dptr = dotbuf + (size_t)(b * NH_ + head) * HW_;

  {
    const int r = tid >> 4, wv = tid & 15;
    const int gh = r0 + r, gw = w0 + wv;
    float logit[KK_];
    float m = -1e30f;
#pragma unroll
    for (int i = 0; i < 7; ++i) {
      int hr = gh + i; if (hr >= H_) hr -= H_;
      const float* drow = dptr + hr * W_;
#pragma unroll
      for (int j = 0; j < 7; ++j) {
        int wc = gw + j; if (wc >= W_) wc -= W_;
        const float l = drow[wc] + rpb[head * KK_ + i * 7 + j];
        logit[i * 7 + j] = l;
        m = fmaxf(m, l);
      }
    }
    float s = 0.f;
#pragma unroll
    for (int o = 0; o < KK_; ++o) {
      const float e = __expf(logit[o] - m);
      s += e;
      at[o * 256 + tid] = e;
    }
    rsum[tid] = 1.0f / s;
  }
  __syncthreads();

  const int c4  = tid & 7;
  const int seg = tid >> 3;
  const int r   = seg >> 1;
  const int sx  = (seg & 1) * 8;
  const int gh  = r0 + r;
  const int pxb = r * 16 + sx;
  const _Float16* vb = vbuf + (size_t)(b * NH_ + head) * HW_ * HD_ + c4 * 4;

  float4 acc[8];
#pragma unroll
  for (int xx = 0; xx < 8; ++xx) acc[xx] = make_float4(0.f, 0.f, 0.f, 0.f);

  for (int i = 0; i < 7; ++i) {
    int hr = gh + i; if (hr >= H_) hr -= H_;
    float4 win[14];
#pragma unroll
    for (int t = 0; t < 14; ++t) {
      int wc = w0 + sx + t; if (wc >= W_) wc -= W_;
      const halfx4 hv = *(const halfx4*)(vb + ((size_t)hr * W_ + wc) * HD_);
      win[t] = make_float4((float)hv[0], (float)hv[1], (float)hv[2], (float)hv[3]);
    }
#pragma unroll
    for (int j = 0; j < 7; ++j) {
      const float* arow = at + (i * 7 + j) * 256 + pxb;
      const float4 a0 = *(const float4*)arow;
      const float4 a1 = *(const float4*)(arow + 4);
      const float aw[8] = {a0.x, a0.y, a0.z, a0.w, a1.x, a1.y, a1.z, a1.w};
#pragma unroll
      for (int xx = 0; xx < 8; ++xx) {
        acc[xx].x = fmaf(aw[xx], win[xx + j].x, acc[xx].x);
        acc[xx].y = fmaf(aw[xx], win[xx + j].y, acc[xx].y);
        acc[xx].z = fmaf(aw[xx], win[xx + j].z, acc[xx].z);
        acc[xx].w = fmaf(aw[xx], win[xx + j].w, acc[xx].w);
      }
    }
  }

  // out: (B,HW,C) fp16, c = head*32 + c4*4 .. +3 (8B aligned)
  const size_t obase =
      ((size_t)b * HW_ + (size_t)gh * W_ + (w0 + sx)) * C_ + head * HD_ + c4 * 4;
#pragma unroll
  for (int xx = 0; xx < 8; ++xx) {
    const float rs = rsum[pxb + xx];
    halfx4 hv;
    hv[0] = (_Float16)(acc[xx].x * rs);
    hv[1] = (_Float16)(acc[xx].y * rs);
    hv[2] = (_Float16)(acc[xx].z * rs);
    hv[3] = (_Float16)(acc[xx].w * rs);
    *(halfx4*)(aof + obase + (size_t)xx * C_) = hv;
  }
}

// ---------------- K3: proj via fp16 MFMA + NHWC -> NCHW -------------------
// Block = 64 px, 4 waves; wave w -> oc in [w*32, w*32+32). No LDS, no barrier.
// R6: single fp16 ao plane + fp16 weights + mfma_f32_16x16x32_f16 (measured
// win vs bf16 hi/lo split, keep).
__global__ __launch_bounds__(256, 2) void k_proj(
    const _Float16* __restrict__ aof, const _Float16* __restrict__ pwf,
    const float* __restrict__ pb, float* __restrict__ out)
{
  const int tid = threadIdx.x;
  const int b   = blockIdx.x / 196;
  const int hw0 = (blockIdx.x % 196) * 64;
  const int w    = __builtin_amdgcn_readfirstlane(tid >> 6);
  const int l    = tid & 63;
  const int m16  = l & 15;
  const int quad = l >> 4;

  floatx4 acc[2][4];
#pragma unroll
  for (int t = 0; t < 2; ++t)
#pragma unroll
    for (int p = 0; p < 4; ++p) acc[t][p] = (floatx4){0.f, 0.f, 0.f, 0.f};

  const size_t pxbase = (size_t)b * HW_ + hw0;

  for (int ks = 0; ks < 4; ++ks) {
    half8 bb[4];
#pragma unroll
    for (int p = 0; p < 4; ++p) {
      const size_t off = (pxbase + p * 16 + m16) * C_ + ks * 32 + quad * 8;
      bb[p] = *(const half8*)(aof + off);
    }
#pragma unroll
    for (int t = 0; t < 2; ++t) {
      const size_t woff = (size_t)(w * 32 + t * 16 + m16) * C_ + ks * 32 + quad * 8;
      const half8 wa = *(const half8*)(pwf + woff);
#pragma unroll
      for (int p = 0; p < 4; ++p) {
        acc[t][p] = __builtin_amdgcn_mfma_f32_16x16x32_f16(wa, bb[p], acc[t][p], 0, 0, 0);
      }
    }
  }

#pragma unroll
  for (int t = 0; t < 2; ++t) {
    float bias[4];
#pragma unroll
    for (int r = 0; r < 4; ++r) bias[r] = pb[w * 32 + t * 16 + quad * 4 + r];
#pragma unroll
    for (int p = 0; p < 4; ++p) {
#pragma unroll
      for (int r = 0; r < 4; ++r) {
        const int oc = w * 32 + t * 16 + quad * 4 + r;
        out[(size_t)b * C_ * HW_ + (size_t)oc * HW_ + hw0 + p * 16 + m16] =
            acc[t][p][r] + bias[r];
      }
    }
  }
}

extern "C" void kernel_launch(void* const* d_in, const int* in_sizes, int n_in,
                              void* d_out, int out_size, void* d_ws, size_t ws_size,
                              hipStream_t stream) {
  const float* x   = (const float*)d_in[0];
  const float* qw  = (const float*)d_in[1];
  const float* qb  = (const float*)d_in[2];
  const float* rpb = (const float*)d_in[3];
  const float* pw  = (const float*)d_in[4];
  const float* pb  = (const float*)d_in[5];
  float* out = (float*)d_out;

  _Float16* vbuf = (_Float16*)d_ws;                    // N*C fp16 (25.7 MB)
  float* dotb = (float*)(vbuf + (size_t)N_ * C_);      // N*NH fp32 (1.6 MB)
  _Float16* aof = (_Float16*)(dotb + (size_t)N_ * NH_); // N*C fp16 (25.7 MB)
  _Float16* qwf = aof + (size_t)N_ * C_;               // 384*128 fp16
  _Float16* pwf = qwf + 384 * C_;                      // 128*128 fp16

  hipLaunchKernelGGL(k_wt,   dim3(192), dim3(256), 0, stream, qw, pw, qwf, pwf);
  hipLaunchKernelGGL(k_qkv,  dim3(N_ / 64), dim3(256), 0, stream, x, qwf, qb, vbuf, dotb);
  hipLaunchKernelGGL(k_attn, dim3(NH_ * B_ * 49), dim3(256), 0, stream, vbuf, dotb, rpb, aof);
  hipLaunchKernelGGL(k_proj, dim3(N_ / 64), dim3(256), 0, stream, aof, pwf, pb, out);
}